// Round 7
// baseline (204.392 us; speedup 1.0000x reference)
//
#include <hip/hip_runtime.h>

#define N_NODES 100000
#define N_EDGES 1600000
#define IN_DIM 256
#define OUT_DIM 32

#define SB_SHIFT 8                          // super-bucket = dst >> 8 (256 nodes)
#define NSB ((N_NODES + 255) >> 8)          // 391
#define SBCAP 4480                          // mean 4092 + ~6 sigma
#define EBLK 4096                           // edges per part1 block
#define NB1 ((N_EDGES + EBLK - 1) / EBLK)   // 391
#define NREP 8                              // deg_out histogram replicas

// ---------------------------------------------------------------------------
// k_deg: out-degree histogram, 8 replicas to cut contention + cross-XCD
// line ping-pong (blockIdx&7 ~ XCD id under round-robin dispatch; perf
// heuristic only, correctness independent of mapping).
// ---------------------------------------------------------------------------
__global__ __launch_bounds__(512) void k_deg(const int* __restrict__ src,
                                             int* __restrict__ rep) {
    int i = blockIdx.x * 512 + threadIdx.x;
    if (i < N_EDGES)
        atomicAdd(&rep[(blockIdx.x & (NREP - 1)) * N_NODES + src[i]], 1);
}

// ---------------------------------------------------------------------------
// k_part1: block-local histogram over 391 super-buckets, one global claim
// per (block,bucket), scatter payloads into private windows. No global
// atomics in the edge loops anymore (deg_out moved to k_deg).
// ---------------------------------------------------------------------------
__global__ __launch_bounds__(512) void k_part1(const int* __restrict__ src,
                                               const int* __restrict__ dst,
                                               int* __restrict__ gcnt,
                                               unsigned* __restrict__ gsb) {
    __shared__ int hist[NSB];
    __shared__ int bbase[NSB];
    __shared__ int cur[NSB];
    const int tid = threadIdx.x;
    const int e0 = blockIdx.x * EBLK;
    const int eend = min(e0 + EBLK, N_EDGES);

    for (int i = tid; i < NSB; i += 512) { hist[i] = 0; cur[i] = 0; }
    __syncthreads();

    // pass A: local histogram (8 iters/thread, LDS atomics only)
    for (int e = e0 + tid; e < eend; e += 512)
        atomicAdd(&hist[dst[e] >> SB_SHIFT], 1);
    __syncthreads();

    // claim contiguous window per bucket
    for (int i = tid; i < NSB; i += 512)
        bbase[i] = atomicAdd(&gcnt[i], hist[i]);
    __syncthreads();

    // pass B: re-read (L2-hot) and scatter into private windows
    for (int e = e0 + tid; e < eend; e += 512) {
        int d = dst[e];
        int s = src[e];
        int r = d >> SB_SHIFT;
        int lp = atomicAdd(&cur[r], 1);
        int pos = bbase[r] + lp;
        if (pos < SBCAP)   // defensive; P(overflow) ~ 1e-7
            gsb[(size_t)r * SBCAP + pos] = ((unsigned)(d & 255) << 17) | (unsigned)s;
    }
}

// ---------------------------------------------------------------------------
// k_scanb: exclusive scan of gcnt[391] -> sbase (single block)
// ---------------------------------------------------------------------------
__global__ __launch_bounds__(512) void k_scanb(const int* __restrict__ gcnt,
                                               int* __restrict__ sbase) {
    __shared__ int s[512];
    int tid = threadIdx.x;
    int v = (tid < NSB) ? min(gcnt[tid], SBCAP) : 0;
    s[tid] = v;
    __syncthreads();
    #pragma unroll
    for (int off = 1; off < 512; off <<= 1) {
        int t = (tid >= off) ? s[tid - off] : 0;
        __syncthreads();
        s[tid] += t;
        __syncthreads();
    }
    if (tid < NSB) sbase[tid] = s[tid] - v;
}

// ---------------------------------------------------------------------------
// k_gemm: h = (x @ W) * norm_src. W in LDS, no K-loop barriers, 4x4 thread
// tile. Epilogue sums the 8 deg_out replicas.
// ---------------------------------------------------------------------------
__global__ __launch_bounds__(256) void k_gemm(const float* __restrict__ x,
                                              const float* __restrict__ W,
                                              const int* __restrict__ rep,
                                              float* __restrict__ h) {
    __shared__ float Wl[IN_DIM][OUT_DIM];  // 32 KB

    const int tid = threadIdx.x;
    {
        float4* Wl4 = reinterpret_cast<float4*>(&Wl[0][0]);
        const float4* W4 = reinterpret_cast<const float4*>(W);
        #pragma unroll
        for (int i = 0; i < 8; ++i)
            Wl4[tid + i * 256] = W4[tid + i * 256];
    }

    const int rg = tid >> 3;
    const int cg = tid & 7;
    const int row0 = blockIdx.x * 128 + rg * 4;
    const int co = cg * 4;

    const float4* xp[4];
    #pragma unroll
    for (int r = 0; r < 4; ++r) {
        int rr = row0 + r;
        if (rr > N_NODES - 1) rr = N_NODES - 1;
        xp[r] = reinterpret_cast<const float4*>(&x[(size_t)rr * IN_DIM]);
    }

    float acc[4][4];
    #pragma unroll
    for (int r = 0; r < 4; ++r)
        #pragma unroll
        for (int c = 0; c < 4; ++c) acc[r][c] = 0.f;

    __syncthreads();

    #pragma unroll 4
    for (int k4 = 0; k4 < IN_DIM / 4; ++k4) {
        float4 w0 = *reinterpret_cast<const float4*>(&Wl[k4 * 4 + 0][co]);
        float4 w1 = *reinterpret_cast<const float4*>(&Wl[k4 * 4 + 1][co]);
        float4 w2 = *reinterpret_cast<const float4*>(&Wl[k4 * 4 + 2][co]);
        float4 w3 = *reinterpret_cast<const float4*>(&Wl[k4 * 4 + 3][co]);
        #pragma unroll
        for (int r = 0; r < 4; ++r) {
            float4 xv = xp[r][k4];
            acc[r][0] += xv.x * w0.x + xv.y * w1.x + xv.z * w2.x + xv.w * w3.x;
            acc[r][1] += xv.x * w0.y + xv.y * w1.y + xv.z * w2.y + xv.w * w3.y;
            acc[r][2] += xv.x * w0.z + xv.y * w1.z + xv.z * w2.z + xv.w * w3.z;
            acc[r][3] += xv.x * w0.w + xv.y * w1.w + xv.z * w2.w + xv.w * w3.w;
        }
    }

    #pragma unroll
    for (int r = 0; r < 4; ++r) {
        int grow = row0 + r;
        if (grow < N_NODES) {
            int dg = 0;
            #pragma unroll
            for (int t = 0; t < NREP; ++t) dg += rep[t * N_NODES + grow];
            float nrm = rsqrtf((float)(dg > 1 ? dg : 1));
            float4 v = make_float4(acc[r][0] * nrm, acc[r][1] * nrm,
                                   acc[r][2] * nrm, acc[r][3] * nrm);
            *reinterpret_cast<float4*>(&h[(size_t)grow * OUT_DIM + co]) = v;
        }
    }
}

// ---------------------------------------------------------------------------
// k_part2: one block (512 thr) per super-bucket; exact counting sort over
// 256 nodes; block-private esrc segment. Emits row_ptr/deg_in coalesced.
// ---------------------------------------------------------------------------
__global__ __launch_bounds__(512) void k_part2(const int* __restrict__ gcnt,
                                               const int* __restrict__ sbase,
                                               const unsigned* __restrict__ gsb,
                                               int* __restrict__ row_ptr,
                                               int* __restrict__ deg_in,
                                               int* __restrict__ esrc) {
    __shared__ int hist[256];
    __shared__ int pref[256];
    __shared__ int cur[256];
    const int r = blockIdx.x;
    const int tid = threadIdx.x;
    int cnt = gcnt[r];
    if (cnt > SBCAP) cnt = SBCAP;
    const unsigned* bp = gsb + (size_t)r * SBCAP;
    const int base = sbase[r];

    if (tid < 256) { hist[tid] = 0; cur[tid] = 0; }
    __syncthreads();

    for (int i = tid; i < cnt; i += 512)
        atomicAdd(&hist[bp[i] >> 17], 1);
    __syncthreads();

    // exclusive scan of hist[256] (first 256 threads active; all sync)
    int v = 0;
    if (tid < 256) { v = hist[tid]; pref[tid] = v; }
    __syncthreads();
    #pragma unroll
    for (int off = 1; off < 256; off <<= 1) {
        int t = (tid < 256 && tid >= off) ? pref[tid - off] : 0;
        __syncthreads();
        if (tid < 256) pref[tid] += t;
        __syncthreads();
    }

    if (tid < 256) {
        int excl = pref[tid] - v;
        int n = (r << SB_SHIFT) + tid;
        if (n < N_NODES) {
            row_ptr[n] = base + excl;
            deg_in[n] = v;
        }
        pref[tid] = excl;
    }
    __syncthreads();

    for (int i = tid; i < cnt; i += 512) {
        unsigned pay = bp[i];
        int l = (int)(pay >> 17);
        int lp = atomicAdd(&cur[l], 1);
        esrc[base + pref[l] + lp] = (int)(pay & 0x1FFFF);
    }
}

// ---------------------------------------------------------------------------
// k_gather: wave per node, 8 edges/round (lane = edge<3b> x colquad<3b>),
// shfl_xor reduce, fused norm_dst + bias.
// ---------------------------------------------------------------------------
__global__ __launch_bounds__(256) void k_gather(const int* __restrict__ esrc,
                                                const int* __restrict__ row_ptr,
                                                const int* __restrict__ deg_in,
                                                const float* __restrict__ h,
                                                const float* __restrict__ bias,
                                                float* __restrict__ out) {
    int node = (blockIdx.x * 256 + threadIdx.x) >> 6;
    if (node >= N_NODES) return;
    int lane = threadIdx.x & 63;
    int j0 = lane >> 3;   // edge slot 0..7
    int q  = lane & 7;    // col quad 0..7

    int start = row_ptr[node];
    int deg = deg_in[node];

    float4 acc = make_float4(0.f, 0.f, 0.f, 0.f);
    int rounds = (deg + 7) >> 3;
    for (int rr = 0; rr < rounds; ++rr) {
        int j = rr * 8 + j0;
        if (j < deg) {
            int s = esrc[start + j];
            float4 hv = *reinterpret_cast<const float4*>(&h[(size_t)s * OUT_DIM + q * 4]);
            acc.x += hv.x; acc.y += hv.y; acc.z += hv.z; acc.w += hv.w;
        }
    }
    #pragma unroll
    for (int m = 8; m <= 32; m <<= 1) {
        acc.x += __shfl_xor(acc.x, m);
        acc.y += __shfl_xor(acc.y, m);
        acc.z += __shfl_xor(acc.z, m);
        acc.w += __shfl_xor(acc.w, m);
    }
    if (j0 == 0) {
        float nrm = rsqrtf((float)(deg > 1 ? deg : 1));
        float4 bb = *reinterpret_cast<const float4*>(&bias[q * 4]);
        float4 o = make_float4(acc.x * nrm + bb.x, acc.y * nrm + bb.y,
                               acc.z * nrm + bb.z, acc.w * nrm + bb.w);
        *reinterpret_cast<float4*>(&out[(size_t)node * OUT_DIM + q * 4]) = o;
    }
}

// ---------------------------------------------------------------------------
extern "C" void kernel_launch(void* const* d_in, const int* in_sizes, int n_in,
                              void* d_out, int out_size, void* d_ws, size_t ws_size,
                              hipStream_t stream) {
    const float* x   = (const float*)d_in[0];
    const int*   src = (const int*)d_in[1];
    const int*   dst = (const int*)d_in[2];
    const float* W   = (const float*)d_in[3];
    const float* b   = (const float*)d_in[4];
    float* out = (float*)d_out;

    // ws (ints): rep[8N] gcnt[NSB] sbase[NSB] row_ptr[N] deg_in[N] pad[2]
    //            h f32[N*32] | gsb u32[NSB*SBCAP] | esrc i32[E]
    int* rep     = (int*)d_ws;
    int* gcnt    = rep + NREP * N_NODES;
    int* sbase   = gcnt + NSB;
    int* row_ptr = sbase + NSB;
    int* deg_in  = row_ptr + N_NODES;
    int* pad     = deg_in + N_NODES;             // int offset 1000782
    float* h     = (float*)(pad + 2);            // 1000784 ints -> 16B aligned
    unsigned* gsb = (unsigned*)(h + (size_t)N_NODES * OUT_DIM);
    int* esrc    = (int*)(gsb + (size_t)NSB * SBCAP);

    // rep and gcnt are adjacent: one memset covers both
    hipMemsetAsync(rep, 0, (NREP * N_NODES + NSB) * sizeof(int), stream);

    k_deg<<<(N_EDGES + 511) / 512, 512, 0, stream>>>(src, rep);

    k_part1<<<NB1, 512, 0, stream>>>(src, dst, gcnt, gsb);

    k_scanb<<<1, 512, 0, stream>>>(gcnt, sbase);

    k_gemm<<<(N_NODES + 127) / 128, 256, 0, stream>>>(x, W, rep, h);

    k_part2<<<NSB, 512, 0, stream>>>(gcnt, sbase, gsb, row_ptr, deg_in, esrc);

    k_gather<<<(N_NODES * 64 + 255) / 256, 256, 0, stream>>>(esrc, row_ptr, deg_in, h, b, out);
}

// Round 8
// 185.599 us; speedup vs baseline: 1.1013x; 1.1013x over previous
//
#include <hip/hip_runtime.h>

#define N_NODES 100000
#define N_EDGES 1600000
#define IN_DIM 256
#define OUT_DIM 32

#define SB_SHIFT 8                          // super-bucket = dst >> 8 (256 nodes)
#define NSB ((N_NODES + 255) >> 8)          // 391
#define SBCAP 4480                          // mean 4092 + ~6 sigma
#define EBLK 4096                           // edges per part1 block
#define NB1 ((N_EDGES + EBLK - 1) / EBLK)   // 391
#define NREP 8                              // deg_out histogram replicas

typedef __attribute__((ext_vector_type(8))) short short8;
typedef __attribute__((ext_vector_type(16))) float f32x16;

#define WT_STRIDE 264    // 256 + 8 pad (bf16 elems) -> 4-way LDS conflict only

__device__ inline unsigned short f2bf(float f) {
    unsigned u = __float_as_uint(f);
    unsigned r = u + 0x7FFF + ((u >> 16) & 1);   // round-to-nearest-even
    return (unsigned short)(r >> 16);
}

// ---------------------------------------------------------------------------
// k_deg: out-degree histogram, 8 replicas (cuts contention + XCD ping-pong)
// ---------------------------------------------------------------------------
__global__ __launch_bounds__(512) void k_deg(const int* __restrict__ src,
                                             int* __restrict__ rep) {
    int i = blockIdx.x * 512 + threadIdx.x;
    if (i < N_EDGES)
        atomicAdd(&rep[(blockIdx.x & (NREP - 1)) * N_NODES + src[i]], 1);
}

// ---------------------------------------------------------------------------
// k_part1: block-local histogram over 391 super-buckets, one global claim
// per (block,bucket), scatter payloads into private windows.
// ---------------------------------------------------------------------------
__global__ __launch_bounds__(512) void k_part1(const int* __restrict__ src,
                                               const int* __restrict__ dst,
                                               int* __restrict__ gcnt,
                                               unsigned* __restrict__ gsb) {
    __shared__ int hist[NSB];
    __shared__ int bbase[NSB];
    __shared__ int cur[NSB];
    const int tid = threadIdx.x;
    const int e0 = blockIdx.x * EBLK;
    const int eend = min(e0 + EBLK, N_EDGES);

    for (int i = tid; i < NSB; i += 512) { hist[i] = 0; cur[i] = 0; }
    __syncthreads();

    for (int e = e0 + tid; e < eend; e += 512)
        atomicAdd(&hist[dst[e] >> SB_SHIFT], 1);
    __syncthreads();

    for (int i = tid; i < NSB; i += 512)
        bbase[i] = atomicAdd(&gcnt[i], hist[i]);
    __syncthreads();

    for (int e = e0 + tid; e < eend; e += 512) {
        int d = dst[e];
        int s = src[e];
        int r = d >> SB_SHIFT;
        int lp = atomicAdd(&cur[r], 1);
        int pos = bbase[r] + lp;
        if (pos < SBCAP)
            gsb[(size_t)r * SBCAP + pos] = ((unsigned)(d & 255) << 17) | (unsigned)s;
    }
}

// ---------------------------------------------------------------------------
// k_scanb: exclusive scan of gcnt[391] -> sbase (single block)
// ---------------------------------------------------------------------------
__global__ __launch_bounds__(512) void k_scanb(const int* __restrict__ gcnt,
                                               int* __restrict__ sbase) {
    __shared__ int s[512];
    int tid = threadIdx.x;
    int v = (tid < NSB) ? min(gcnt[tid], SBCAP) : 0;
    s[tid] = v;
    __syncthreads();
    #pragma unroll
    for (int off = 1; off < 512; off <<= 1) {
        int t = (tid >= off) ? s[tid - off] : 0;
        __syncthreads();
        s[tid] += t;
        __syncthreads();
    }
    if (tid < NSB) sbase[tid] = s[tid] - v;
}

// ---------------------------------------------------------------------------
// k_gemm (R7: MFMA bf16). h = (x @ W) * norm_src.
// Wave = 32 rows x 32 cols via v_mfma_f32_32x32x16_bf16, K in 16 chunks.
// A: per-lane 8 consecutive f32 of its row -> cvt bf16 (lines fully consumed
//    by lane pairs l / l+32). No barriers in the K-loop.
// B: W^T bf16 in LDS (padded), one ds_read_b128 per chunk, same for all waves.
// Fragment layouts per HW-verified guide:
//   A[i][k]: i = l&31, k = 8*(l>>5)+j
//   C/D:     col = l&31, row = (r&3) + 8*(r>>2) + 4*(l>>5)
// ---------------------------------------------------------------------------
__global__ __launch_bounds__(256) void k_gemm(const float* __restrict__ x,
                                              const float* __restrict__ W,
                                              const int* __restrict__ rep,
                                              float* __restrict__ h) {
    __shared__ unsigned short WT[32 * WT_STRIDE];   // 16896 B

    const int tid = threadIdx.x;
    // stage W^T as bf16 (coalesced global read, one-time scattered LDS write)
    #pragma unroll
    for (int i = 0; i < 32; ++i) {
        int idx = tid + i * 256;            // k = idx>>5, c = idx&31
        WT[(idx & 31) * WT_STRIDE + (idx >> 5)] = f2bf(W[idx]);
    }
    __syncthreads();

    const int wv = tid >> 6;
    const int lane = tid & 63;
    const int col = lane & 31;
    const int hi = lane >> 5;

    const int row0 = blockIdx.x * 128 + wv * 32;
    int grow = row0 + col;
    int growc = grow < N_NODES ? grow : N_NODES - 1;
    const float4* xrow = reinterpret_cast<const float4*>(x + (size_t)growc * IN_DIM);

    f32x16 acc = {0.f,0.f,0.f,0.f,0.f,0.f,0.f,0.f,
                  0.f,0.f,0.f,0.f,0.f,0.f,0.f,0.f};

    #pragma unroll 4
    for (int t = 0; t < 16; ++t) {
        int k4 = t * 4 + hi * 2;            // float4 index; k = t*16 + hi*8
        float4 p0 = xrow[k4];
        float4 p1 = xrow[k4 + 1];
        short8 a;
        a[0] = (short)f2bf(p0.x); a[1] = (short)f2bf(p0.y);
        a[2] = (short)f2bf(p0.z); a[3] = (short)f2bf(p0.w);
        a[4] = (short)f2bf(p1.x); a[5] = (short)f2bf(p1.y);
        a[6] = (short)f2bf(p1.z); a[7] = (short)f2bf(p1.w);
        short8 bfr = *reinterpret_cast<const short8*>(
            &WT[col * WT_STRIDE + t * 16 + hi * 8]);
        acc = __builtin_amdgcn_mfma_f32_32x32x16_bf16(a, bfr, acc, 0, 0, 0);
    }

    // norm for row row0+col (coalesced rep reads), distribute via shfl
    int dg = 0;
    #pragma unroll
    for (int rr = 0; rr < NREP; ++rr) dg += rep[rr * N_NODES + growc];
    float nrm = rsqrtf((float)(dg > 1 ? dg : 1));

    #pragma unroll
    for (int r = 0; r < 16; ++r) {
        int rowi = (r & 3) + 8 * (r >> 2) + 4 * hi;
        float nr = __shfl(nrm, rowi, 64);   // lane 'rowi' owns that row's nrm
        int go = row0 + rowi;
        if (go < N_NODES)
            h[(size_t)go * OUT_DIM + col] = acc[r] * nr;
    }
}

// ---------------------------------------------------------------------------
// k_part2: one block (512 thr) per super-bucket; exact counting sort over
// 256 nodes; block-private esrc segment. Emits row_ptr/deg_in coalesced.
// ---------------------------------------------------------------------------
__global__ __launch_bounds__(512) void k_part2(const int* __restrict__ gcnt,
                                               const int* __restrict__ sbase,
                                               const unsigned* __restrict__ gsb,
                                               int* __restrict__ row_ptr,
                                               int* __restrict__ deg_in,
                                               int* __restrict__ esrc) {
    __shared__ int hist[256];
    __shared__ int pref[256];
    __shared__ int cur[256];
    const int r = blockIdx.x;
    const int tid = threadIdx.x;
    int cnt = gcnt[r];
    if (cnt > SBCAP) cnt = SBCAP;
    const unsigned* bp = gsb + (size_t)r * SBCAP;
    const int base = sbase[r];

    if (tid < 256) { hist[tid] = 0; cur[tid] = 0; }
    __syncthreads();

    for (int i = tid; i < cnt; i += 512)
        atomicAdd(&hist[bp[i] >> 17], 1);
    __syncthreads();

    int v = 0;
    if (tid < 256) { v = hist[tid]; pref[tid] = v; }
    __syncthreads();
    #pragma unroll
    for (int off = 1; off < 256; off <<= 1) {
        int t = (tid < 256 && tid >= off) ? pref[tid - off] : 0;
        __syncthreads();
        if (tid < 256) pref[tid] += t;
        __syncthreads();
    }

    if (tid < 256) {
        int excl = pref[tid] - v;
        int n = (r << SB_SHIFT) + tid;
        if (n < N_NODES) {
            row_ptr[n] = base + excl;
            deg_in[n] = v;
        }
        pref[tid] = excl;
    }
    __syncthreads();

    for (int i = tid; i < cnt; i += 512) {
        unsigned pay = bp[i];
        int l = (int)(pay >> 17);
        int lp = atomicAdd(&cur[l], 1);
        esrc[base + pref[l] + lp] = (int)(pay & 0x1FFFF);
    }
}

// ---------------------------------------------------------------------------
// k_gather: wave per node, 8 edges/round (lane = edge<3b> x colquad<3b>),
// shfl_xor reduce, fused norm_dst + bias.
// ---------------------------------------------------------------------------
__global__ __launch_bounds__(256) void k_gather(const int* __restrict__ esrc,
                                                const int* __restrict__ row_ptr,
                                                const int* __restrict__ deg_in,
                                                const float* __restrict__ h,
                                                const float* __restrict__ bias,
                                                float* __restrict__ out) {
    int node = (blockIdx.x * 256 + threadIdx.x) >> 6;
    if (node >= N_NODES) return;
    int lane = threadIdx.x & 63;
    int j0 = lane >> 3;   // edge slot 0..7
    int q  = lane & 7;    // col quad 0..7

    int start = row_ptr[node];
    int deg = deg_in[node];

    float4 acc = make_float4(0.f, 0.f, 0.f, 0.f);
    int rounds = (deg + 7) >> 3;
    for (int rr = 0; rr < rounds; ++rr) {
        int j = rr * 8 + j0;
        if (j < deg) {
            int s = esrc[start + j];
            float4 hv = *reinterpret_cast<const float4*>(&h[(size_t)s * OUT_DIM + q * 4]);
            acc.x += hv.x; acc.y += hv.y; acc.z += hv.z; acc.w += hv.w;
        }
    }
    #pragma unroll
    for (int m = 8; m <= 32; m <<= 1) {
        acc.x += __shfl_xor(acc.x, m);
        acc.y += __shfl_xor(acc.y, m);
        acc.z += __shfl_xor(acc.z, m);
        acc.w += __shfl_xor(acc.w, m);
    }
    if (j0 == 0) {
        float nrm = rsqrtf((float)(deg > 1 ? deg : 1));
        float4 bb = *reinterpret_cast<const float4*>(&bias[q * 4]);
        float4 o = make_float4(acc.x * nrm + bb.x, acc.y * nrm + bb.y,
                               acc.z * nrm + bb.z, acc.w * nrm + bb.w);
        *reinterpret_cast<float4*>(&out[(size_t)node * OUT_DIM + q * 4]) = o;
    }
}

// ---------------------------------------------------------------------------
extern "C" void kernel_launch(void* const* d_in, const int* in_sizes, int n_in,
                              void* d_out, int out_size, void* d_ws, size_t ws_size,
                              hipStream_t stream) {
    const float* x   = (const float*)d_in[0];
    const int*   src = (const int*)d_in[1];
    const int*   dst = (const int*)d_in[2];
    const float* W   = (const float*)d_in[3];
    const float* b   = (const float*)d_in[4];
    float* out = (float*)d_out;

    // ws (ints): rep[8N] gcnt[NSB] sbase[NSB] row_ptr[N] deg_in[N] pad[2]
    //            h f32[N*32] | gsb u32[NSB*SBCAP] | esrc i32[E]
    int* rep     = (int*)d_ws;
    int* gcnt    = rep + NREP * N_NODES;
    int* sbase   = gcnt + NSB;
    int* row_ptr = sbase + NSB;
    int* deg_in  = row_ptr + N_NODES;
    int* pad     = deg_in + N_NODES;
    float* h     = (float*)(pad + 2);            // 16B aligned
    unsigned* gsb = (unsigned*)(h + (size_t)N_NODES * OUT_DIM);
    int* esrc    = (int*)(gsb + (size_t)NSB * SBCAP);

    hipMemsetAsync(rep, 0, (NREP * N_NODES + NSB) * sizeof(int), stream);

    k_deg<<<(N_EDGES + 511) / 512, 512, 0, stream>>>(src, rep);

    k_part1<<<NB1, 512, 0, stream>>>(src, dst, gcnt, gsb);

    k_scanb<<<1, 512, 0, stream>>>(gcnt, sbase);

    k_gemm<<<(N_NODES + 127) / 128, 256, 0, stream>>>(x, W, rep, h);

    k_part2<<<NSB, 512, 0, stream>>>(gcnt, sbase, gsb, row_ptr, deg_in, esrc);

    k_gather<<<(N_NODES * 64 + 255) / 256, 256, 0, stream>>>(esrc, row_ptr, deg_in, h, b, out);
}

// Round 9
// 144.693 us; speedup vs baseline: 1.4126x; 1.2827x over previous
//
#include <hip/hip_runtime.h>

#define N_NODES 100000
#define N_EDGES 1600000
#define IN_DIM 256
#define OUT_DIM 32

#define SB_SHIFT 8                          // super-bucket = node >> 8 (256 nodes)
#define NSB ((N_NODES + 255) >> 8)          // 391
#define SBCAP 4480                          // mean 4092 + ~6 sigma
#define EBLK 4096                           // edges per part1 block
#define NB1 ((N_EDGES + EBLK - 1) / EBLK)   // 391

typedef __attribute__((ext_vector_type(8))) short short8;
typedef __attribute__((ext_vector_type(16))) float f32x16;

#define WT_STRIDE 264    // 256 + 8 pad (bf16 elems)

__device__ inline unsigned short f2bf(float f) {
    unsigned u = __float_as_uint(f);
    unsigned r = u + 0x7FFF + ((u >> 16) & 1);   // round-to-nearest-even
    return (unsigned short)(r >> 16);
}

// ---------------------------------------------------------------------------
// k_part1 (R8: dual partition). Block-local histograms over super-buckets of
// BOTH dst (u32 payload: (dst&255)<<17|src) and src (u8 payload: src&255).
// One global window claim per (block,bucket,side). No random global atomics.
// ---------------------------------------------------------------------------
__global__ __launch_bounds__(512) void k_part1(const int* __restrict__ src,
                                               const int* __restrict__ dst,
                                               int* __restrict__ gcnt,
                                               int* __restrict__ gcnt_s,
                                               unsigned* __restrict__ gsb,
                                               unsigned char* __restrict__ gss) {
    __shared__ int hist[NSB], bbase[NSB], cur[NSB];
    __shared__ int hist_s[NSB], bbase_s[NSB], cur_s[NSB];
    const int tid = threadIdx.x;
    const int e0 = blockIdx.x * EBLK;
    const int eend = min(e0 + EBLK, N_EDGES);

    for (int i = tid; i < NSB; i += 512) {
        hist[i] = 0; cur[i] = 0; hist_s[i] = 0; cur_s[i] = 0;
    }
    __syncthreads();

    // pass A: both histograms (LDS atomics only)
    for (int e = e0 + tid; e < eend; e += 512) {
        atomicAdd(&hist[dst[e] >> SB_SHIFT], 1);
        atomicAdd(&hist_s[src[e] >> SB_SHIFT], 1);
    }
    __syncthreads();

    // claim contiguous windows (global atomics on 2x391 hot counters only)
    for (int i = tid; i < NSB; i += 512) {
        bbase[i]   = atomicAdd(&gcnt[i], hist[i]);
        bbase_s[i] = atomicAdd(&gcnt_s[i], hist_s[i]);
    }
    __syncthreads();

    // pass B: re-read (L3-hot) and scatter into private windows
    for (int e = e0 + tid; e < eend; e += 512) {
        int d = dst[e];
        int s = src[e];
        int r = d >> SB_SHIFT;
        int lp = atomicAdd(&cur[r], 1);
        int pos = bbase[r] + lp;
        if (pos < SBCAP)
            gsb[(size_t)r * SBCAP + pos] = ((unsigned)(d & 255) << 17) | (unsigned)s;
        int rs = s >> SB_SHIFT;
        int lp2 = atomicAdd(&cur_s[rs], 1);
        int pos2 = bbase_s[rs] + lp2;
        if (pos2 < SBCAP)
            gss[(size_t)rs * SBCAP + pos2] = (unsigned char)(s & 255);
    }
}

// ---------------------------------------------------------------------------
// k_deg2: per-super-bucket u8 histogram -> deg_out (coalesced write)
// ---------------------------------------------------------------------------
__global__ __launch_bounds__(256) void k_deg2(const int* __restrict__ gcnt_s,
                                              const unsigned char* __restrict__ gss,
                                              int* __restrict__ deg_out) {
    __shared__ int hist[256];
    const int r = blockIdx.x;
    const int tid = threadIdx.x;
    hist[tid] = 0;
    __syncthreads();
    int cnt = gcnt_s[r];
    if (cnt > SBCAP) cnt = SBCAP;
    const unsigned char* bp = gss + (size_t)r * SBCAP;
    for (int i = tid; i < cnt; i += 256)
        atomicAdd(&hist[bp[i]], 1);
    __syncthreads();
    int n = (r << SB_SHIFT) + tid;
    if (n < N_NODES) deg_out[n] = hist[tid];
}

// ---------------------------------------------------------------------------
// k_scanb: exclusive scan of gcnt[391] -> sbase (single block)
// ---------------------------------------------------------------------------
__global__ __launch_bounds__(512) void k_scanb(const int* __restrict__ gcnt,
                                               int* __restrict__ sbase) {
    __shared__ int s[512];
    int tid = threadIdx.x;
    int v = (tid < NSB) ? min(gcnt[tid], SBCAP) : 0;
    s[tid] = v;
    __syncthreads();
    #pragma unroll
    for (int off = 1; off < 512; off <<= 1) {
        int t = (tid >= off) ? s[tid - off] : 0;
        __syncthreads();
        s[tid] += t;
        __syncthreads();
    }
    if (tid < NSB) sbase[tid] = s[tid] - v;
}

// ---------------------------------------------------------------------------
// k_gemm (MFMA bf16): h = (x @ W) * norm_src. Layouts HW-verified in R8.
// ---------------------------------------------------------------------------
__global__ __launch_bounds__(256) void k_gemm(const float* __restrict__ x,
                                              const float* __restrict__ W,
                                              const int* __restrict__ deg_out,
                                              float* __restrict__ h) {
    __shared__ unsigned short WT[32 * WT_STRIDE];   // 16896 B

    const int tid = threadIdx.x;
    #pragma unroll
    for (int i = 0; i < 32; ++i) {
        int idx = tid + i * 256;            // k = idx>>5, c = idx&31
        WT[(idx & 31) * WT_STRIDE + (idx >> 5)] = f2bf(W[idx]);
    }
    __syncthreads();

    const int wv = tid >> 6;
    const int lane = tid & 63;
    const int col = lane & 31;
    const int hi = lane >> 5;

    const int row0 = blockIdx.x * 128 + wv * 32;
    int grow = row0 + col;
    int growc = grow < N_NODES ? grow : N_NODES - 1;
    const float4* xrow = reinterpret_cast<const float4*>(x + (size_t)growc * IN_DIM);

    f32x16 acc = {0.f,0.f,0.f,0.f,0.f,0.f,0.f,0.f,
                  0.f,0.f,0.f,0.f,0.f,0.f,0.f,0.f};

    #pragma unroll 4
    for (int t = 0; t < 16; ++t) {
        int k4 = t * 4 + hi * 2;            // k = t*16 + hi*8
        float4 p0 = xrow[k4];
        float4 p1 = xrow[k4 + 1];
        short8 a;
        a[0] = (short)f2bf(p0.x); a[1] = (short)f2bf(p0.y);
        a[2] = (short)f2bf(p0.z); a[3] = (short)f2bf(p0.w);
        a[4] = (short)f2bf(p1.x); a[5] = (short)f2bf(p1.y);
        a[6] = (short)f2bf(p1.z); a[7] = (short)f2bf(p1.w);
        short8 bfr = *reinterpret_cast<const short8*>(
            &WT[col * WT_STRIDE + t * 16 + hi * 8]);
        acc = __builtin_amdgcn_mfma_f32_32x32x16_bf16(a, bfr, acc, 0, 0, 0);
    }

    int dg = deg_out[growc];
    float nrm = rsqrtf((float)(dg > 1 ? dg : 1));

    #pragma unroll
    for (int r = 0; r < 16; ++r) {
        int rowi = (r & 3) + 8 * (r >> 2) + 4 * hi;
        float nr = __shfl(nrm, rowi, 64);
        int go = row0 + rowi;
        if (go < N_NODES)
            h[(size_t)go * OUT_DIM + col] = acc[r] * nr;
    }
}

// ---------------------------------------------------------------------------
// k_part2: per-super-bucket exact counting sort -> esrc, row_ptr, deg_in
// ---------------------------------------------------------------------------
__global__ __launch_bounds__(512) void k_part2(const int* __restrict__ gcnt,
                                               const int* __restrict__ sbase,
                                               const unsigned* __restrict__ gsb,
                                               int* __restrict__ row_ptr,
                                               int* __restrict__ deg_in,
                                               int* __restrict__ esrc) {
    __shared__ int hist[256];
    __shared__ int pref[256];
    __shared__ int cur[256];
    const int r = blockIdx.x;
    const int tid = threadIdx.x;
    int cnt = gcnt[r];
    if (cnt > SBCAP) cnt = SBCAP;
    const unsigned* bp = gsb + (size_t)r * SBCAP;
    const int base = sbase[r];

    if (tid < 256) { hist[tid] = 0; cur[tid] = 0; }
    __syncthreads();

    for (int i = tid; i < cnt; i += 512)
        atomicAdd(&hist[bp[i] >> 17], 1);
    __syncthreads();

    int v = 0;
    if (tid < 256) { v = hist[tid]; pref[tid] = v; }
    __syncthreads();
    #pragma unroll
    for (int off = 1; off < 256; off <<= 1) {
        int t = (tid < 256 && tid >= off) ? pref[tid - off] : 0;
        __syncthreads();
        if (tid < 256) pref[tid] += t;
        __syncthreads();
    }

    if (tid < 256) {
        int excl = pref[tid] - v;
        int n = (r << SB_SHIFT) + tid;
        if (n < N_NODES) {
            row_ptr[n] = base + excl;
            deg_in[n] = v;
        }
        pref[tid] = excl;
    }
    __syncthreads();

    for (int i = tid; i < cnt; i += 512) {
        unsigned pay = bp[i];
        int l = (int)(pay >> 17);
        int lp = atomicAdd(&cur[l], 1);
        esrc[base + pref[l] + lp] = (int)(pay & 0x1FFFF);
    }
}

// ---------------------------------------------------------------------------
// k_gather: wave per node, 8 edges/round, shfl_xor reduce, fused norm+bias
// ---------------------------------------------------------------------------
__global__ __launch_bounds__(256) void k_gather(const int* __restrict__ esrc,
                                                const int* __restrict__ row_ptr,
                                                const int* __restrict__ deg_in,
                                                const float* __restrict__ h,
                                                const float* __restrict__ bias,
                                                float* __restrict__ out) {
    int node = (blockIdx.x * 256 + threadIdx.x) >> 6;
    if (node >= N_NODES) return;
    int lane = threadIdx.x & 63;
    int j0 = lane >> 3;   // edge slot 0..7
    int q  = lane & 7;    // col quad 0..7

    int start = row_ptr[node];
    int deg = deg_in[node];

    float4 acc = make_float4(0.f, 0.f, 0.f, 0.f);
    int rounds = (deg + 7) >> 3;
    for (int rr = 0; rr < rounds; ++rr) {
        int j = rr * 8 + j0;
        if (j < deg) {
            int s = esrc[start + j];
            float4 hv = *reinterpret_cast<const float4*>(&h[(size_t)s * OUT_DIM + q * 4]);
            acc.x += hv.x; acc.y += hv.y; acc.z += hv.z; acc.w += hv.w;
        }
    }
    #pragma unroll
    for (int m = 8; m <= 32; m <<= 1) {
        acc.x += __shfl_xor(acc.x, m);
        acc.y += __shfl_xor(acc.y, m);
        acc.z += __shfl_xor(acc.z, m);
        acc.w += __shfl_xor(acc.w, m);
    }
    if (j0 == 0) {
        float nrm = rsqrtf((float)(deg > 1 ? deg : 1));
        float4 bb = *reinterpret_cast<const float4*>(&bias[q * 4]);
        float4 o = make_float4(acc.x * nrm + bb.x, acc.y * nrm + bb.y,
                               acc.z * nrm + bb.z, acc.w * nrm + bb.w);
        *reinterpret_cast<float4*>(&out[(size_t)node * OUT_DIM + q * 4]) = o;
    }
}

// ---------------------------------------------------------------------------
extern "C" void kernel_launch(void* const* d_in, const int* in_sizes, int n_in,
                              void* d_out, int out_size, void* d_ws, size_t ws_size,
                              hipStream_t stream) {
    const float* x   = (const float*)d_in[0];
    const int*   src = (const int*)d_in[1];
    const int*   dst = (const int*)d_in[2];
    const float* W   = (const float*)d_in[3];
    const float* b   = (const float*)d_in[4];
    float* out = (float*)d_out;

    // ws (ints): gcnt[NSB] gcnt_s[NSB] sbase[NSB] deg_out[N] row_ptr[N]
    //            deg_in[N] pad -> h f32[N*32] | gsb u32[NSB*SBCAP] |
    //            esrc i32[E] | gss u8[NSB*SBCAP]
    int* gcnt    = (int*)d_ws;
    int* gcnt_s  = gcnt + NSB;
    int* sbase   = gcnt_s + NSB;
    int* deg_out = sbase + NSB;
    int* row_ptr = deg_out + N_NODES;
    int* deg_in  = row_ptr + N_NODES;
    int* pad     = deg_in + N_NODES;             // 301173 ints
    float* h     = (float*)(pad + 3);            // 301176 ints -> 16B aligned
    unsigned* gsb = (unsigned*)(h + (size_t)N_NODES * OUT_DIM);
    int* esrc    = (int*)(gsb + (size_t)NSB * SBCAP);
    unsigned char* gss = (unsigned char*)(esrc + N_EDGES);

    // only the two counter arrays need zeroing (adjacent)
    hipMemsetAsync(gcnt, 0, 2 * NSB * sizeof(int), stream);

    k_part1<<<NB1, 512, 0, stream>>>(src, dst, gcnt, gcnt_s, gsb, gss);

    k_deg2<<<NSB, 256, 0, stream>>>(gcnt_s, gss, deg_out);

    k_scanb<<<1, 512, 0, stream>>>(gcnt, sbase);

    k_gemm<<<(N_NODES + 127) / 128, 256, 0, stream>>>(x, W, deg_out, h);

    k_part2<<<NSB, 512, 0, stream>>>(gcnt, sbase, gsb, row_ptr, deg_in, esrc);

    k_gather<<<(N_NODES * 64 + 255) / 256, 256, 0, stream>>>(esrc, row_ptr, deg_in, h, b, out);
}